// Round 1
// baseline (157.182 us; speedup 1.0000x reference)
//
#include <hip/hip_runtime.h>
#include <math.h>

#define N_NODES 10000
#define N_EDGES 160000

// Workspace layout (floats):
//   [0      .. 10000)  s1   = scatter(ew * x[src])
//   [10000  .. 20000)  deg  = scatter(ew)
//   [20000  .. 30000)  t2   = scatter(ew * s1[src])
//   [30000  .. 40000)  A    = scatter(ew * t2[src])
//   [40000  .. 50000)  B    = scatter(ew * deg[src])
//   [50000  .. 50512)  p = (W1row @ W2) @ W3
//   [50512  .. 51024)  q = (b1 @ W2) @ W3
//   [51024  .. 51536)  r = b2 @ W3

__global__ void small_vecs_kernel(const float* __restrict__ W1, const float* __restrict__ b1,
                                  const float* __restrict__ W2, const float* __restrict__ b2,
                                  const float* __restrict__ W3,
                                  float* __restrict__ p, float* __restrict__ q,
                                  float* __restrict__ r) {
    __shared__ float su[256], sv[256];
    int tid = threadIdx.x;  // 512 threads
    if (tid < 256) {
        float uu = 0.f, vv = 0.f;
        for (int j = 0; j < 128; ++j) {
            float w2 = W2[j * 256 + tid];
            uu = fmaf(W1[j], w2, uu);
            vv = fmaf(b1[j], w2, vv);
        }
        su[tid] = uu;
        sv[tid] = vv;
    }
    __syncthreads();
    float pp = 0.f, qq = 0.f, rr = 0.f;
    for (int k = 0; k < 256; ++k) {
        float w3 = W3[k * 512 + tid];  // coalesced across tid
        pp = fmaf(su[k], w3, pp);
        qq = fmaf(sv[k], w3, qq);
        rr = fmaf(b2[k], w3, rr);
    }
    p[tid] = pp;
    q[tid] = qq;
    r[tid] = rr;
}

__global__ void edge_pass1_kernel(const int* __restrict__ src, const int* __restrict__ dst,
                                  const float* __restrict__ ew, const float* __restrict__ x,
                                  float* __restrict__ s1, float* __restrict__ deg) {
    int e = blockIdx.x * blockDim.x + threadIdx.x;
    if (e < N_EDGES) {
        int s = src[e], d = dst[e];
        float w = ew[e];
        atomicAdd(&s1[d], w * x[s]);
        atomicAdd(&deg[d], w);
    }
}

__global__ void edge_pass2_kernel(const int* __restrict__ src, const int* __restrict__ dst,
                                  const float* __restrict__ ew,
                                  const float* __restrict__ s1, float* __restrict__ t2) {
    int e = blockIdx.x * blockDim.x + threadIdx.x;
    if (e < N_EDGES) {
        int s = src[e], d = dst[e];
        atomicAdd(&t2[d], ew[e] * s1[s]);
    }
}

__global__ void edge_pass3_kernel(const int* __restrict__ src, const int* __restrict__ dst,
                                  const float* __restrict__ ew,
                                  const float* __restrict__ t2, const float* __restrict__ deg,
                                  float* __restrict__ A, float* __restrict__ B) {
    int e = blockIdx.x * blockDim.x + threadIdx.x;
    if (e < N_EDGES) {
        int s = src[e], d = dst[e];
        float w = ew[e];
        atomicAdd(&A[d], w * t2[s]);
        atomicAdd(&B[d], w * deg[s]);
    }
}

__global__ void output_kernel(const float* __restrict__ A, const float* __restrict__ B,
                              const float* __restrict__ deg,
                              const float* __restrict__ p, const float* __restrict__ q,
                              const float* __restrict__ r, const float* __restrict__ b3,
                              float* __restrict__ out) {
    // one thread per float4: N_NODES * 512 / 4 = 1,280,000 threads
    int idx = blockIdx.x * blockDim.x + threadIdx.x;
    int node = idx >> 7;       // 128 float4s per node
    int j = idx & 127;         // float4 index within the 512-vec
    float a = A[node], b = B[node], dg = deg[node];
    float4 P = ((const float4*)p)[j];
    float4 Q = ((const float4*)q)[j];
    float4 R = ((const float4*)r)[j];
    float4 B3 = ((const float4*)b3)[j];
    float4 o;
    float zx = fmaf(a, P.x, fmaf(b, Q.x, fmaf(dg, R.x, B3.x)));
    float zy = fmaf(a, P.y, fmaf(b, Q.y, fmaf(dg, R.y, B3.y)));
    float zz = fmaf(a, P.z, fmaf(b, Q.z, fmaf(dg, R.z, B3.z)));
    float zw = fmaf(a, P.w, fmaf(b, Q.w, fmaf(dg, R.w, B3.w)));
    o.x = 1.f / (1.f + __expf(-zx));
    o.y = 1.f / (1.f + __expf(-zy));
    o.z = 1.f / (1.f + __expf(-zz));
    o.w = 1.f / (1.f + __expf(-zw));
    ((float4*)out)[idx] = o;
}

extern "C" void kernel_launch(void* const* d_in, const int* in_sizes, int n_in,
                              void* d_out, int out_size, void* d_ws, size_t ws_size,
                              hipStream_t stream) {
    const float* x  = (const float*)d_in[0];
    const int*   ei = (const int*)d_in[1];
    const float* ew = (const float*)d_in[2];
    const float* W1 = (const float*)d_in[3];
    const float* b1 = (const float*)d_in[4];
    const float* W2 = (const float*)d_in[5];
    const float* b2 = (const float*)d_in[6];
    const float* W3 = (const float*)d_in[7];
    const float* b3 = (const float*)d_in[8];
    float* out = (float*)d_out;

    float* ws  = (float*)d_ws;
    float* s1  = ws;
    float* deg = ws + 10000;
    float* t2  = ws + 20000;
    float* A   = ws + 30000;
    float* B   = ws + 40000;
    float* p   = ws + 50000;
    float* q   = ws + 50512;
    float* r   = ws + 51024;

    const int* src = ei;            // edge_index[0]
    const int* dst = ei + N_EDGES;  // edge_index[1]

    // zero the scatter accumulators (ws is poisoned to 0xAA before every call)
    hipMemsetAsync(d_ws, 0, 50000 * sizeof(float), stream);

    small_vecs_kernel<<<1, 512, 0, stream>>>(W1, b1, W2, b2, W3, p, q, r);

    const int EB = 256, EG = (N_EDGES + EB - 1) / EB;
    edge_pass1_kernel<<<EG, EB, 0, stream>>>(src, dst, ew, x, s1, deg);
    edge_pass2_kernel<<<EG, EB, 0, stream>>>(src, dst, ew, s1, t2);
    edge_pass3_kernel<<<EG, EB, 0, stream>>>(src, dst, ew, t2, deg, A, B);

    const int total4 = N_NODES * 512 / 4;  // 1,280,000
    output_kernel<<<total4 / 256, 256, 0, stream>>>(A, B, deg, p, q, r, b3, out);
}